// Round 7
// baseline (9695.409 us; speedup 1.0000x reference)
//
#include <hip/hip_runtime.h>
#include <hip/hip_cooperative_groups.h>

namespace cg = cooperative_groups;

#define Bb 64
#define Tt 512
#define Dd 512
#define Hh 2048
#define Oo 7
#define NKT 80          // 2560 / 32
#define NWG 256
#define NTHR 256
#define NSLOT_BAR 32    // barrier split: 32 slots x 8 arrivals
#define BARPAD 32       // u32 stride per slot (128B line)

typedef short bf16x8 __attribute__((ext_vector_type(8)));
typedef float f32x4 __attribute__((ext_vector_type(4)));

__device__ __forceinline__ unsigned short f2bf(float f) {
  unsigned u = __float_as_uint(f);
  return (unsigned short)((u + 0x7FFFu + ((u >> 16) & 1u)) >> 16);
}
__device__ __forceinline__ float bf2f(unsigned short s) {
  return __uint_as_float(((unsigned)s) << 16);
}
__device__ __forceinline__ float sigm(float x) { return 1.0f / (1.0f + __expf(-x)); }
__device__ __forceinline__ float tanh_(float x) {
  x = fminf(15.0f, fmaxf(-15.0f, x));
  float e = __expf(2.0f * x);
  return (e - 1.0f) / (e + 1.0f);
}

__global__ void __launch_bounds__(NTHR, 2) lstm_fused(
    const float* __restrict__ x,
    const float* __restrict__ W_ih, const float* __restrict__ b_ih,
    const float* __restrict__ W_hh, const float* __restrict__ b_hh,
    const float* __restrict__ W_h0, const float* __restrict__ b_h0,
    const float* __restrict__ W_c0, const float* __restrict__ b_c0,
    const float* __restrict__ W_fc, const float* __restrict__ b_fc,
    float* __restrict__ out,
    short* __restrict__ Wbf,            // [8192*2560] bf16, fragment-linear
    unsigned short* __restrict__ Hbuf,  // [513][64][2048] bf16
    float* __restrict__ cbuf,           // [64][2048]
    float* __restrict__ meanx,          // [64][512]
    float* __restrict__ bsum,           // [8192]
    unsigned short* __restrict__ xbf,   // [64][512][512] bf16
    unsigned* __restrict__ bar)         // [513][NSLOT_BAR][BARPAD]
{
  const int wg = blockIdx.x, tid = threadIdx.x;
  const int gtid = wg * NTHR + tid;
  cg::grid_group grid = cg::this_grid();
  __shared__ float smem[Oo * Hh];  // 57344 B, reused per phase

  // ---------- phase 0a: mean_x over T ----------
  {
    int b = wg >> 2;
    int d = ((wg & 3) << 7) + (tid & 127);
    int th = tid >> 7;
    const float* xp = x + (size_t)b * Tt * Dd + d;
    float s = 0.f;
    for (int t = th * 256; t < th * 256 + 256; ++t) s += xp[(size_t)t * Dd];
    smem[tid] = s;
    __syncthreads();
    if (th == 0) meanx[b * Dd + d] = (smem[tid] + smem[tid + 128]) * (1.0f / Tt);
    __syncthreads();
  }

  // ---------- phase 0b: weight swizzle + x->bf16 + bias sums + barrier zero ----------
  {
    const int NSLOT = (8192 * 2560) / 8;
    for (int slot = gtid; slot < NSLOT; slot += NWG * NTHR) {
      int lane = slot & 63;
      int fr = slot >> 6;                 // ((wg*2+nt)*80 + kt)
      int kt = fr % 80;
      int ntw = fr / 80;                  // wg*2 + nt
      int nl = ((ntw & 1) << 4) + (lane & 15);
      int w = ntw >> 1;
      int row = ((nl >> 3) << 11) + (w << 3) + (nl & 7);   // gate*2048 + w*8 + j
      int kb = (kt << 5) + ((lane >> 4) << 3);
      const float* src = (kb < 512) ? (W_ih + (size_t)row * 512 + kb)
                                    : (W_hh + (size_t)row * 2048 + (kb - 512));
      float4 u0 = *reinterpret_cast<const float4*>(src);
      float4 u1 = *reinterpret_cast<const float4*>(src + 4);
      bf16x8 v;
      v[0] = (short)f2bf(u0.x); v[1] = (short)f2bf(u0.y);
      v[2] = (short)f2bf(u0.z); v[3] = (short)f2bf(u0.w);
      v[4] = (short)f2bf(u1.x); v[5] = (short)f2bf(u1.y);
      v[6] = (short)f2bf(u1.z); v[7] = (short)f2bf(u1.w);
      *reinterpret_cast<bf16x8*>(Wbf + (size_t)slot * 8) = v;
    }
    const int NX = (Bb * Tt * Dd) / 8;
    for (int s = gtid; s < NX; s += NWG * NTHR) {
      const float* p = x + (size_t)s * 8;
      float4 u0 = *reinterpret_cast<const float4*>(p);
      float4 u1 = *reinterpret_cast<const float4*>(p + 4);
      bf16x8 v;
      v[0] = (short)f2bf(u0.x); v[1] = (short)f2bf(u0.y);
      v[2] = (short)f2bf(u0.z); v[3] = (short)f2bf(u0.w);
      v[4] = (short)f2bf(u1.x); v[5] = (short)f2bf(u1.y);
      v[6] = (short)f2bf(u1.z); v[7] = (short)f2bf(u1.w);
      *reinterpret_cast<bf16x8*>((short*)xbf + (size_t)s * 8) = v;
    }
    for (int i = gtid; i < 513 * NSLOT_BAR * BARPAD; i += NWG * NTHR) bar[i] = 0u;
    if (gtid < 8192) bsum[gtid] = b_ih[gtid] + b_hh[gtid];
  }
  grid.sync();

  // ---------- phase 0c: h0 / c0 ----------
  {
    for (int q = tid; q < 1024; q += NTHR) {
      int which = q >> 9;                 // 0 -> h0, 1 -> c0
      int b = (q >> 3) & 63;
      int j = q & 7;
      int n = (wg << 3) + j;
      const float* Wr = (which ? W_c0 : W_h0) + (size_t)n * 512;
      const float* mx = meanx + b * 512;
      float acc0 = which ? b_c0[n] : b_h0[n];
      for (int d = 0; d < 512; ++d) acc0 += mx[d] * Wr[d];
      if (which) cbuf[b * Hh + n] = acc0;
      else       Hbuf[(size_t)b * Hh + n] = f2bf(acc0);
    }
  }
  grid.sync();

  // ---------- pin FULL per-wave weight slice (w0 + w1 = 160 VGPRs) ----------
  const int wave = tid >> 6, lane = tid & 63;
  const int ml = lane & 15;
  const int kg = lane >> 4;
  const short* wb0 = Wbf + (size_t)(wg * 2) * NKT * 512;  // frag stride = 512 shorts
  const short* wb1 = wb0 + (size_t)NKT * 512;

  bf16x8 w0x[4], w0h[16], w1x[4], w1h[16];
#pragma unroll
  for (int i = 0; i < 4; ++i) {
    int kt = (wave << 2) + i;
    w0x[i] = *reinterpret_cast<const bf16x8*>(wb0 + ((size_t)kt << 9) + (lane << 3));
    w1x[i] = *reinterpret_cast<const bf16x8*>(wb1 + ((size_t)kt << 9) + (lane << 3));
  }
#pragma unroll
  for (int i = 0; i < 16; ++i) {
    int kt = 16 + (wave << 4) + i;
    w0h[i] = *reinterpret_cast<const bf16x8*>(wb0 + ((size_t)kt << 9) + (lane << 3));
    w1h[i] = *reinterpret_cast<const bf16x8*>(wb1 + ((size_t)kt << 9) + (lane << 3));
  }

  // ---------- hoist loop-invariant cell state into registers ----------
  const int cb = tid >> 2, cj0 = (tid & 3) << 1;
  const int cn0 = (wg << 3) + cj0;
  float cv0 = cbuf[cb * Hh + cn0], cv1 = cbuf[cb * Hh + cn0 + 1];
  const float bi0 = bsum[cn0],     bf0 = bsum[2048 + cn0];
  const float bg0 = bsum[4096 + cn0], bo0 = bsum[6144 + cn0];
  const float bi1 = bsum[cn0 + 1],     bf1 = bsum[2048 + cn0 + 1];
  const float bg1 = bsum[4096 + cn0 + 1], bo1 = bsum[6144 + cn0 + 1];

  f32x4 acc[4][2];
#pragma unroll
  for (int mt = 0; mt < 4; ++mt) {
    acc[mt][0] = (f32x4){0.f, 0.f, 0.f, 0.f};
    acc[mt][1] = (f32x4){0.f, 0.f, 0.f, 0.f};
  }

  // x-part of step tx+1's gates (recurrence-independent; runs under the barrier)
  auto xpart = [&](int tx) {
#pragma unroll
    for (int i = 0; i < 4; ++i) {
      int kt = (wave << 2) + i;
      int kk = (kt << 5) + (kg << 3);
      const unsigned short* xb = xbf + (size_t)tx * Dd + kk;
      bf16x8 afr[4];
#pragma unroll
      for (int mt = 0; mt < 4; ++mt) {
        int m = (mt << 4) + ml;
        afr[mt] = *reinterpret_cast<const bf16x8*>(xb + (size_t)m * (Tt * Dd));
      }
#pragma unroll
      for (int mt = 0; mt < 4; ++mt) {
        acc[mt][0] = __builtin_amdgcn_mfma_f32_16x16x32_bf16(afr[mt], w0x[i], acc[mt][0], 0, 0, 0);
        acc[mt][1] = __builtin_amdgcn_mfma_f32_16x16x32_bf16(afr[mt], w1x[i], acc[mt][1], 0, 0, 0);
      }
    }
  };

  // prologue: x-part for step 1 (x index 0)
  xpart(0);

  // ---------- main recurrence ----------
  for (int t = 1; t <= Tt; ++t) {
    if (t > 1) {
      // wait for h_{t-1}: relaxed agent-scope atomic LOAD poll (no RMW contention)
      if (tid < NSLOT_BAR) {
        while (__hip_atomic_load(&bar[((size_t)(t - 1) * NSLOT_BAR + tid) * BARPAD],
                                 __ATOMIC_RELAXED, __HIP_MEMORY_SCOPE_AGENT) < 8u)
          __builtin_amdgcn_s_sleep(4);
      }
      __syncthreads();
    }
    // h-part: 16 h k-tiles per wave, weights all in registers
#pragma unroll
    for (int i = 0; i < 16; ++i) {
      int kk = (((wave << 4) + i) << 5) + (kg << 3);
      const unsigned short* hb = Hbuf + (size_t)(t - 1) * (Bb * Hh) + kk;
      bf16x8 afr[4];
#pragma unroll
      for (int mt = 0; mt < 4; ++mt) {
        int m = (mt << 4) + ml;
        afr[mt] = *reinterpret_cast<const bf16x8*>(hb + (size_t)m * Hh);
      }
#pragma unroll
      for (int mt = 0; mt < 4; ++mt) {
        acc[mt][0] = __builtin_amdgcn_mfma_f32_16x16x32_bf16(afr[mt], w0h[i], acc[mt][0], 0, 0, 0);
        acc[mt][1] = __builtin_amdgcn_mfma_f32_16x16x32_bf16(afr[mt], w1h[i], acc[mt][1], 0, 0, 0);
      }
    }
    // partials -> LDS  (D layout: row=(lane>>4)*4+r, col=lane&15)
#pragma unroll
    for (int mt = 0; mt < 4; ++mt) {
      int r0 = (mt << 4) + (kg << 2);
#pragma unroll
      for (int r = 0; r < 4; ++r) {
        smem[((wave << 6) + r0 + r) * 33 + ml] = acc[mt][0][r];
        smem[((wave << 6) + r0 + r) * 33 + 16 + ml] = acc[mt][1][r];
      }
    }
    __syncthreads();
    // cell: reduce 4 wave-partials, LSTM nonlinearity (all-register state)
    unsigned* hout32 = (unsigned*)(Hbuf + (size_t)t * (Bb * Hh));
    {
      float gi0 = 0.f, gf_0 = 0.f, gg0 = 0.f, go0 = 0.f;
      float gi1 = 0.f, gf_1 = 0.f, gg1 = 0.f, go1 = 0.f;
#pragma unroll
      for (int w2 = 0; w2 < 4; ++w2) {
        const float* sp = &smem[((w2 << 6) + cb) * 33];
        gi0 += sp[cj0];          gf_0 += sp[8 + cj0];
        gg0 += sp[16 + cj0];     go0 += sp[24 + cj0];
        gi1 += sp[cj0 + 1];      gf_1 += sp[8 + cj0 + 1];
        gg1 += sp[16 + cj0 + 1]; go1 += sp[24 + cj0 + 1];
      }
      gi0 += bi0; gf_0 += bf0; gg0 += bg0; go0 += bo0;
      gi1 += bi1; gf_1 += bf1; gg1 += bg1; go1 += bo1;
      cv0 = sigm(gf_0) * cv0 + sigm(gi0) * tanh_(gg0);
      cv1 = sigm(gf_1) * cv1 + sigm(gi1) * tanh_(gg1);
      float hv0 = sigm(go0) * tanh_(cv0);
      float hv1 = sigm(go1) * tanh_(cv1);
      unsigned pk = ((unsigned)f2bf(hv1) << 16) | (unsigned)f2bf(hv0);
      __hip_atomic_store(&hout32[(cb * Hh + cn0) >> 1], pk,
                         __ATOMIC_RELAXED, __HIP_MEMORY_SCOPE_AGENT);
    }
    // drain h stores, arrive
    asm volatile("s_waitcnt vmcnt(0)" ::: "memory");
    __syncthreads();
    if (tid == 0)
      __hip_atomic_fetch_add(&bar[((size_t)t * NSLOT_BAR + (wg & (NSLOT_BAR - 1))) * BARPAD], 1u,
                             __ATOMIC_RELAXED, __HIP_MEMORY_SCOPE_AGENT);
    // pipeline: x-part for step t+1 under the barrier wait
#pragma unroll
    for (int mt = 0; mt < 4; ++mt) {
      acc[mt][0] = (f32x4){0.f, 0.f, 0.f, 0.f};
      acc[mt][1] = (f32x4){0.f, 0.f, 0.f, 0.f};
    }
    if (t < Tt) xpart(t);
  }

  // ---------- wait for ALL WGs' step-512 h before reading it (race fix) ----------
  if (tid < NSLOT_BAR) {
    while (__hip_atomic_load(&bar[((size_t)Tt * NSLOT_BAR + tid) * BARPAD],
                             __ATOMIC_RELAXED, __HIP_MEMORY_SCOPE_AGENT) < 8u)
      __builtin_amdgcn_s_sleep(4);
  }
  __syncthreads();

  // ---------- fc epilogue ----------
  for (int i = tid; i < Oo * Hh; i += NTHR) smem[i] = W_fc[i];
  __syncthreads();
  if (gtid < Bb * Tt) {
    int b = gtid & 63, tq = gtid >> 6;
    const unsigned short* hrw = Hbuf + (size_t)(tq + 1) * (Bb * Hh) + (size_t)b * Hh;
    float acco[7];
#pragma unroll
    for (int o = 0; o < 7; ++o) acco[o] = b_fc[o];
    for (int k = 0; k < Hh; k += 8) {
      bf16x8 hv = *reinterpret_cast<const bf16x8*>(hrw + k);
      float hf[8];
#pragma unroll
      for (int e = 0; e < 8; ++e) hf[e] = bf2f((unsigned short)hv[e]);
#pragma unroll
      for (int o = 0; o < 7; ++o) {
        const float* wr = &smem[o * Hh + k];
        float s = 0.f;
#pragma unroll
        for (int e = 0; e < 8; ++e) s += hf[e] * wr[e];
        acco[o] += s;
      }
    }
    float* op = out + ((size_t)b * Tt + tq) * Oo;
#pragma unroll
    for (int o = 0; o < 7; ++o) op[o] = acco[o];
  }
}

extern "C" void kernel_launch(void* const* d_in, const int* in_sizes, int n_in,
                              void* d_out, int out_size, void* d_ws, size_t ws_size,
                              hipStream_t stream) {
  (void)in_sizes; (void)n_in;
  const float* x    = (const float*)d_in[0];
  const float* W_ih = (const float*)d_in[1];
  const float* b_ih = (const float*)d_in[2];
  const float* W_hh = (const float*)d_in[3];
  const float* b_hh = (const float*)d_in[4];
  const float* W_h0 = (const float*)d_in[5];
  const float* b_h0 = (const float*)d_in[6];
  const float* W_c0 = (const float*)d_in[7];
  const float* b_c0 = (const float*)d_in[8];
  const float* W_fc = (const float*)d_in[9];
  const float* b_fc = (const float*)d_in[10];
  float* out = (float*)d_out;

  char* ws = (char*)d_ws;
  size_t off = 0;
  short* Wbf = (short*)(ws + off);            off += (size_t)8192 * 2560 * 2;
  unsigned short* Hbuf = (unsigned short*)(ws + off); off += (size_t)513 * 64 * 2048 * 2;
  float* cbuf = (float*)(ws + off);           off += (size_t)64 * 2048 * 4;
  float* meanx = (float*)(ws + off);          off += (size_t)64 * 512 * 4;
  float* bsum = (float*)(ws + off);           off += (size_t)8192 * 4;
  unsigned short* xbf = (unsigned short*)(ws + off); off += (size_t)64 * 512 * 512 * 2;
  unsigned* bar = (unsigned*)(ws + off);      off += (size_t)513 * NSLOT_BAR * BARPAD * 4;

  if (ws_size < off) {
    hipMemsetAsync(d_out, 0, (size_t)out_size * 4, stream);
    return;
  }

  void* args[] = {&x, &W_ih, &b_ih, &W_hh, &b_hh, &W_h0, &b_h0, &W_c0, &b_c0,
                  &W_fc, &b_fc, &out, &Wbf, &Hbuf, &cbuf, &meanx, &bsum, &xbf, &bar};
  hipLaunchCooperativeKernel((void*)lstm_fused, dim3(NWG), dim3(NTHR), args, 0, stream);
}

// Round 8
// 7137.001 us; speedup vs baseline: 1.3585x; 1.3585x over previous
//
#include <hip/hip_runtime.h>
#include <hip/hip_cooperative_groups.h>

namespace cg = cooperative_groups;

#define Bb 64
#define Tt 512
#define Dd 512
#define Hh 2048
#define Oo 7
#define NKT 80          // 2560 / 32
#define NWG 256
#define NTHR 256

typedef short bf16x8 __attribute__((ext_vector_type(8)));
typedef float f32x4 __attribute__((ext_vector_type(4)));

__device__ __forceinline__ unsigned short f2bf(float f) {
  unsigned u = __float_as_uint(f);
  return (unsigned short)((u + 0x7FFFu + ((u >> 16) & 1u)) >> 16);
}
__device__ __forceinline__ float bf2f(unsigned short s) {
  return __uint_as_float(((unsigned)s) << 16);
}
__device__ __forceinline__ float sigm(float x) { return 1.0f / (1.0f + __expf(-x)); }
__device__ __forceinline__ float tanh_(float x) {
  x = fminf(15.0f, fmaxf(-15.0f, x));
  float e = __expf(2.0f * x);
  return (e - 1.0f) / (e + 1.0f);
}

__global__ void __launch_bounds__(NTHR, 2) lstm_fused(
    const float* __restrict__ x,
    const float* __restrict__ W_ih, const float* __restrict__ b_ih,
    const float* __restrict__ W_hh, const float* __restrict__ b_hh,
    const float* __restrict__ W_h0, const float* __restrict__ b_h0,
    const float* __restrict__ W_c0, const float* __restrict__ b_c0,
    const float* __restrict__ W_fc, const float* __restrict__ b_fc,
    float* __restrict__ out,
    short* __restrict__ Wbf,            // [8192*2560] bf16, fragment-linear
    unsigned short* __restrict__ Hbuf,  // [513][64][2048] bf16
    float* __restrict__ cbuf,           // [64][2048]
    float* __restrict__ meanx,          // [64][512]
    float* __restrict__ bsum,           // [8192]
    unsigned short* __restrict__ xbf,   // [64][512][512] bf16
    unsigned* __restrict__ bar)         // [513][8][32] u32 barrier slots
{
  const int wg = blockIdx.x, tid = threadIdx.x;
  const int gtid = wg * NTHR + tid;
  cg::grid_group grid = cg::this_grid();
  __shared__ float smem[256 * 33];                 // 33792 B: phase0a + partials
  __shared__ alignas(16) short w1lds[NKT * 512];   // 81920 B: w1 slice; fc staging later

  // ---------- phase 0a: mean_x over T ----------
  {
    int b = wg >> 2;
    int d = ((wg & 3) << 7) + (tid & 127);
    int th = tid >> 7;
    const float* xp = x + (size_t)b * Tt * Dd + d;
    float s = 0.f;
    for (int t = th * 256; t < th * 256 + 256; ++t) s += xp[(size_t)t * Dd];
    smem[tid] = s;
    __syncthreads();
    if (th == 0) meanx[b * Dd + d] = (smem[tid] + smem[tid + 128]) * (1.0f / Tt);
    __syncthreads();
  }

  // ---------- phase 0b: weight swizzle + x->bf16 + bias sums + barrier zero ----------
  {
    const int NSLOT = (8192 * 2560) / 8;
    for (int slot = gtid; slot < NSLOT; slot += NWG * NTHR) {
      int lane = slot & 63;
      int fr = slot >> 6;                 // ((wg*2+nt)*80 + kt)
      int kt = fr % 80;
      int ntw = fr / 80;                  // wg*2 + nt
      int nl = ((ntw & 1) << 4) + (lane & 15);
      int w = ntw >> 1;
      int row = ((nl >> 3) << 11) + (w << 3) + (nl & 7);   // gate*2048 + w*8 + j
      int kb = (kt << 5) + ((lane >> 4) << 3);
      const float* src = (kb < 512) ? (W_ih + (size_t)row * 512 + kb)
                                    : (W_hh + (size_t)row * 2048 + (kb - 512));
      float4 u0 = *reinterpret_cast<const float4*>(src);
      float4 u1 = *reinterpret_cast<const float4*>(src + 4);
      bf16x8 v;
      v[0] = (short)f2bf(u0.x); v[1] = (short)f2bf(u0.y);
      v[2] = (short)f2bf(u0.z); v[3] = (short)f2bf(u0.w);
      v[4] = (short)f2bf(u1.x); v[5] = (short)f2bf(u1.y);
      v[6] = (short)f2bf(u1.z); v[7] = (short)f2bf(u1.w);
      *reinterpret_cast<bf16x8*>(Wbf + (size_t)slot * 8) = v;
    }
    const int NX = (Bb * Tt * Dd) / 8;
    for (int s = gtid; s < NX; s += NWG * NTHR) {
      const float* p = x + (size_t)s * 8;
      float4 u0 = *reinterpret_cast<const float4*>(p);
      float4 u1 = *reinterpret_cast<const float4*>(p + 4);
      bf16x8 v;
      v[0] = (short)f2bf(u0.x); v[1] = (short)f2bf(u0.y);
      v[2] = (short)f2bf(u0.z); v[3] = (short)f2bf(u0.w);
      v[4] = (short)f2bf(u1.x); v[5] = (short)f2bf(u1.y);
      v[6] = (short)f2bf(u1.z); v[7] = (short)f2bf(u1.w);
      *reinterpret_cast<bf16x8*>((short*)xbf + (size_t)s * 8) = v;
    }
    for (int i = gtid; i < 513 * 8 * 32; i += NWG * NTHR) bar[i] = 0u;
    if (gtid < 8192) bsum[gtid] = b_ih[gtid] + b_hh[gtid];
  }
  grid.sync();

  // ---------- phase 0c: h0 / c0 ----------
  {
    for (int q = tid; q < 1024; q += NTHR) {
      int which = q >> 9;                 // 0 -> h0, 1 -> c0
      int b = (q >> 3) & 63;
      int j = q & 7;
      int n = (wg << 3) + j;
      const float* Wr = (which ? W_c0 : W_h0) + (size_t)n * 512;
      const float* mx = meanx + b * 512;
      float acc0 = which ? b_c0[n] : b_h0[n];
      for (int d = 0; d < 512; ++d) acc0 += mx[d] * Wr[d];
      if (which) cbuf[b * Hh + n] = acc0;
      else       Hbuf[(size_t)b * Hh + n] = f2bf(acc0);
    }
  }
  grid.sync();

  // ---------- residency: w0 in registers (80 VGPR), w1 slice in LDS (80 KB) ----------
  const int wave = tid >> 6, lane = tid & 63;
  const int ml = lane & 15;
  const int kg = lane >> 4;
  const short* wb0 = Wbf + (size_t)(wg * 2) * NKT * 512;  // frag stride = 512 shorts
  const short* wb1 = wb0 + (size_t)NKT * 512;

  bf16x8 w0x[4], w0h[16];
#pragma unroll
  for (int i = 0; i < 4; ++i) {
    int kt = (wave << 2) + i;
    w0x[i] = *reinterpret_cast<const bf16x8*>(wb0 + ((size_t)kt << 9) + (lane << 3));
  }
#pragma unroll
  for (int i = 0; i < 16; ++i) {
    int kt = 16 + (wave << 4) + i;
    w0h[i] = *reinterpret_cast<const bf16x8*>(wb0 + ((size_t)kt << 9) + (lane << 3));
  }
  for (int i = tid; i < (NKT * 512) / 8; i += NTHR)
    reinterpret_cast<bf16x8*>(w1lds)[i] = reinterpret_cast<const bf16x8*>(wb1)[i];
  __syncthreads();

  // ---------- hoist loop-invariant cell state into registers ----------
  const int cb = tid >> 2, cj0 = (tid & 3) << 1;
  const int cn0 = (wg << 3) + cj0;
  float cv0 = cbuf[cb * Hh + cn0], cv1 = cbuf[cb * Hh + cn0 + 1];
  const float bi0 = bsum[cn0],        bfs0 = bsum[2048 + cn0];
  const float bg0 = bsum[4096 + cn0], bo0 = bsum[6144 + cn0];
  const float bi1 = bsum[cn0 + 1],        bfs1 = bsum[2048 + cn0 + 1];
  const float bg1 = bsum[4096 + cn0 + 1], bo1 = bsum[6144 + cn0 + 1];

  f32x4 acc[4][2];
#pragma unroll
  for (int mt = 0; mt < 4; ++mt) {
    acc[mt][0] = (f32x4){0.f, 0.f, 0.f, 0.f};
    acc[mt][1] = (f32x4){0.f, 0.f, 0.f, 0.f};
  }

  // x-part of step tx+1's gates (recurrence-independent; runs under the barrier)
  auto xpart = [&](int tx) {
#pragma unroll
    for (int i = 0; i < 4; ++i) {
      int kt = (wave << 2) + i;
      int kk = (kt << 5) + (kg << 3);
      const unsigned short* xb = xbf + (size_t)tx * Dd + kk;
      bf16x8 afr[4];
#pragma unroll
      for (int mt = 0; mt < 4; ++mt) {
        int m = (mt << 4) + ml;
        afr[mt] = *reinterpret_cast<const bf16x8*>(xb + (size_t)m * (Tt * Dd));
      }
      bf16x8 q1 = *reinterpret_cast<const bf16x8*>(&w1lds[(kt << 9) + (lane << 3)]);
#pragma unroll
      for (int mt = 0; mt < 4; ++mt) {
        acc[mt][0] = __builtin_amdgcn_mfma_f32_16x16x32_bf16(afr[mt], w0x[i], acc[mt][0], 0, 0, 0);
        acc[mt][1] = __builtin_amdgcn_mfma_f32_16x16x32_bf16(afr[mt], q1, acc[mt][1], 0, 0, 0);
      }
    }
  };

  // prologue: x-part for step 1 (x index 0)
  xpart(0);

  // ---------- main recurrence ----------
  for (int t = 1; t <= Tt; ++t) {
    if (t > 1) {
      // wait for h_{t-1} (r6-proven barrier: RMW poll on 8 slots)
      if (tid < 8) {
        while (__hip_atomic_fetch_add(&bar[((size_t)(t - 1) * 8 + tid) * 32], 0u,
                                      __ATOMIC_RELAXED, __HIP_MEMORY_SCOPE_AGENT) < 32u)
          __builtin_amdgcn_s_sleep(8);
      }
      __syncthreads();
    }
    // h-part: 16 h k-tiles per wave; w0 from regs, w1 from LDS
#pragma unroll
    for (int i = 0; i < 16; ++i) {
      int kt = 16 + (wave << 4) + i;
      int kk = (((wave << 4) + i) << 5) + (kg << 3);
      const unsigned short* hb = Hbuf + (size_t)(t - 1) * (Bb * Hh) + kk;
      bf16x8 afr[4];
#pragma unroll
      for (int mt = 0; mt < 4; ++mt) {
        int m = (mt << 4) + ml;
        afr[mt] = *reinterpret_cast<const bf16x8*>(hb + (size_t)m * Hh);
      }
      bf16x8 q1 = *reinterpret_cast<const bf16x8*>(&w1lds[(kt << 9) + (lane << 3)]);
#pragma unroll
      for (int mt = 0; mt < 4; ++mt) {
        acc[mt][0] = __builtin_amdgcn_mfma_f32_16x16x32_bf16(afr[mt], w0h[i], acc[mt][0], 0, 0, 0);
        acc[mt][1] = __builtin_amdgcn_mfma_f32_16x16x32_bf16(afr[mt], q1, acc[mt][1], 0, 0, 0);
      }
    }
    // partials -> LDS  (D layout: row=(lane>>4)*4+r, col=lane&15)
#pragma unroll
    for (int mt = 0; mt < 4; ++mt) {
      int r0 = (mt << 4) + (kg << 2);
#pragma unroll
      for (int r = 0; r < 4; ++r) {
        smem[((wave << 6) + r0 + r) * 33 + ml] = acc[mt][0][r];
        smem[((wave << 6) + r0 + r) * 33 + 16 + ml] = acc[mt][1][r];
      }
    }
    __syncthreads();
    // cell: reduce 4 wave-partials, LSTM nonlinearity (register cell state)
    unsigned* hout32 = (unsigned*)(Hbuf + (size_t)t * (Bb * Hh));
    {
      float gi0 = 0.f, gf_0 = 0.f, gg0 = 0.f, go0 = 0.f;
      float gi1 = 0.f, gf_1 = 0.f, gg1 = 0.f, go1 = 0.f;
#pragma unroll
      for (int w2 = 0; w2 < 4; ++w2) {
        const float* sp = &smem[((w2 << 6) + cb) * 33];
        gi0 += sp[cj0];          gf_0 += sp[8 + cj0];
        gg0 += sp[16 + cj0];     go0 += sp[24 + cj0];
        gi1 += sp[cj0 + 1];      gf_1 += sp[8 + cj0 + 1];
        gg1 += sp[16 + cj0 + 1]; go1 += sp[24 + cj0 + 1];
      }
      gi0 += bi0; gf_0 += bfs0; gg0 += bg0; go0 += bo0;
      gi1 += bi1; gf_1 += bfs1; gg1 += bg1; go1 += bo1;
      cv0 = sigm(gf_0) * cv0 + sigm(gi0) * tanh_(gg0);
      cv1 = sigm(gf_1) * cv1 + sigm(gi1) * tanh_(gg1);
      float hv0 = sigm(go0) * tanh_(cv0);
      float hv1 = sigm(go1) * tanh_(cv1);
      unsigned pk = ((unsigned)f2bf(hv1) << 16) | (unsigned)f2bf(hv0);
      __hip_atomic_store(&hout32[(cb * Hh + cn0) >> 1], pk,
                         __ATOMIC_RELAXED, __HIP_MEMORY_SCOPE_AGENT);
    }
    // drain h stores, arrive
    asm volatile("s_waitcnt vmcnt(0)" ::: "memory");
    __syncthreads();
    if (tid == 0)
      __hip_atomic_fetch_add(&bar[((size_t)t * 8 + (wg & 7)) * 32], 1u,
                             __ATOMIC_RELAXED, __HIP_MEMORY_SCOPE_AGENT);
    // pipeline: x-part for step t+1 under the barrier wait
#pragma unroll
    for (int mt = 0; mt < 4; ++mt) {
      acc[mt][0] = (f32x4){0.f, 0.f, 0.f, 0.f};
      acc[mt][1] = (f32x4){0.f, 0.f, 0.f, 0.f};
    }
    if (t < Tt) xpart(t);
  }

  // ---------- wait for ALL WGs' step-512 h before reading it (race fix) ----------
  if (tid < 8) {
    while (__hip_atomic_fetch_add(&bar[((size_t)Tt * 8 + tid) * 32], 0u,
                                  __ATOMIC_RELAXED, __HIP_MEMORY_SCOPE_AGENT) < 32u)
      __builtin_amdgcn_s_sleep(8);
  }
  __syncthreads();

  // ---------- fc epilogue (stage W_fc into the w1 LDS region) ----------
  float* wfc_s = (float*)w1lds;
  for (int i = tid; i < Oo * Hh; i += NTHR) wfc_s[i] = W_fc[i];
  __syncthreads();
  if (gtid < Bb * Tt) {
    int b = gtid & 63, tq = gtid >> 6;
    const unsigned short* hrw = Hbuf + (size_t)(tq + 1) * (Bb * Hh) + (size_t)b * Hh;
    float acco[7];
#pragma unroll
    for (int o = 0; o < 7; ++o) acco[o] = b_fc[o];
    for (int k = 0; k < Hh; k += 8) {
      bf16x8 hv = *reinterpret_cast<const bf16x8*>(hrw + k);
      float hf[8];
#pragma unroll
      for (int e = 0; e < 8; ++e) hf[e] = bf2f((unsigned short)hv[e]);
#pragma unroll
      for (int o = 0; o < 7; ++o) {
        const float* wr = &wfc_s[o * Hh + k];
        float s = 0.f;
#pragma unroll
        for (int e = 0; e < 8; ++e) s += hf[e] * wr[e];
        acco[o] += s;
      }
    }
    float* op = out + ((size_t)b * Tt + tq) * Oo;
#pragma unroll
    for (int o = 0; o < 7; ++o) op[o] = acco[o];
  }
}

extern "C" void kernel_launch(void* const* d_in, const int* in_sizes, int n_in,
                              void* d_out, int out_size, void* d_ws, size_t ws_size,
                              hipStream_t stream) {
  (void)in_sizes; (void)n_in;
  const float* x    = (const float*)d_in[0];
  const float* W_ih = (const float*)d_in[1];
  const float* b_ih = (const float*)d_in[2];
  const float* W_hh = (const float*)d_in[3];
  const float* b_hh = (const float*)d_in[4];
  const float* W_h0 = (const float*)d_in[5];
  const float* b_h0 = (const float*)d_in[6];
  const float* W_c0 = (const float*)d_in[7];
  const float* b_c0 = (const float*)d_in[8];
  const float* W_fc = (const float*)d_in[9];
  const float* b_fc = (const float*)d_in[10];
  float* out = (float*)d_out;

  char* ws = (char*)d_ws;
  size_t off = 0;
  short* Wbf = (short*)(ws + off);            off += (size_t)8192 * 2560 * 2;
  unsigned short* Hbuf = (unsigned short*)(ws + off); off += (size_t)513 * 64 * 2048 * 2;
  float* cbuf = (float*)(ws + off);           off += (size_t)64 * 2048 * 4;
  float* meanx = (float*)(ws + off);          off += (size_t)64 * 512 * 4;
  float* bsum = (float*)(ws + off);           off += (size_t)8192 * 4;
  unsigned short* xbf = (unsigned short*)(ws + off); off += (size_t)64 * 512 * 512 * 2;
  unsigned* bar = (unsigned*)(ws + off);      off += (size_t)513 * 8 * 32 * 4;

  if (ws_size < off) {
    hipMemsetAsync(d_out, 0, (size_t)out_size * 4, stream);
    return;
  }

  void* args[] = {&x, &W_ih, &b_ih, &W_hh, &b_hh, &W_h0, &b_h0, &W_c0, &b_c0,
                  &W_fc, &b_fc, &out, &Wbf, &Hbuf, &cbuf, &meanx, &bsum, &xbf, &bar};
  hipLaunchCooperativeKernel((void*)lstm_fused, dim3(NWG), dim3(NTHR), args, 0, stream);
}

// Round 9
// 6714.832 us; speedup vs baseline: 1.4439x; 1.0629x over previous
//
#include <hip/hip_runtime.h>
#include <hip/hip_cooperative_groups.h>

namespace cg = cooperative_groups;

#define Bb 64
#define Tt 512
#define Dd 512
#define Hh 2048
#define Oo 7
#define NKT 80          // 2560 / 32
#define NWG 256
#define NTHR 256

typedef short bf16x8 __attribute__((ext_vector_type(8)));
typedef float f32x4 __attribute__((ext_vector_type(4)));

__device__ __forceinline__ unsigned short f2bf(float f) {
  unsigned u = __float_as_uint(f);
  return (unsigned short)((u + 0x7FFFu + ((u >> 16) & 1u)) >> 16);
}
__device__ __forceinline__ float bf2f(unsigned short s) {
  return __uint_as_float(((unsigned)s) << 16);
}
__device__ __forceinline__ float sigm(float x) { return 1.0f / (1.0f + __expf(-x)); }
__device__ __forceinline__ float tanh_(float x) {
  x = fminf(15.0f, fmaxf(-15.0f, x));
  float e = __expf(2.0f * x);
  return (e - 1.0f) / (e + 1.0f);
}

__global__ void __launch_bounds__(NTHR, 2) lstm_fused(
    const float* __restrict__ x,
    const float* __restrict__ W_ih, const float* __restrict__ b_ih,
    const float* __restrict__ W_hh, const float* __restrict__ b_hh,
    const float* __restrict__ W_h0, const float* __restrict__ b_h0,
    const float* __restrict__ W_c0, const float* __restrict__ b_c0,
    const float* __restrict__ W_fc, const float* __restrict__ b_fc,
    float* __restrict__ out,
    short* __restrict__ Wbf,            // [8192*2560] bf16, fragment-linear
    unsigned short* __restrict__ Hbuf,  // [513][64][2048] bf16
    float* __restrict__ cbuf,           // [64][2048]
    float* __restrict__ meanx,          // [64][512]
    float* __restrict__ bsum,           // [8192]
    unsigned short* __restrict__ xbf,   // [64][512][512] bf16
    unsigned* __restrict__ flags)       // [256] per-WG step flag (monotonic)
{
  const int wg = blockIdx.x, tid = threadIdx.x;
  const int gtid = wg * NTHR + tid;
  cg::grid_group grid = cg::this_grid();
  __shared__ float smem[Oo * Hh];  // 57344 B, reused per phase

  // ---------- phase 0a: mean_x over T ----------
  {
    int b = wg >> 2;
    int d = ((wg & 3) << 7) + (tid & 127);
    int th = tid >> 7;
    const float* xp = x + (size_t)b * Tt * Dd + d;
    float s = 0.f;
    for (int t = th * 256; t < th * 256 + 256; ++t) s += xp[(size_t)t * Dd];
    smem[tid] = s;
    __syncthreads();
    if (th == 0) meanx[b * Dd + d] = (smem[tid] + smem[tid + 128]) * (1.0f / Tt);
    __syncthreads();
  }

  // ---------- phase 0b: weight swizzle + x->bf16 + bias sums + flag zero ----------
  {
    const int NSLOT = (8192 * 2560) / 8;
    for (int slot = gtid; slot < NSLOT; slot += NWG * NTHR) {
      int lane = slot & 63;
      int fr = slot >> 6;                 // ((wg*2+nt)*80 + kt)
      int kt = fr % 80;
      int ntw = fr / 80;                  // wg*2 + nt
      int nl = ((ntw & 1) << 4) + (lane & 15);
      int w = ntw >> 1;
      int row = ((nl >> 3) << 11) + (w << 3) + (nl & 7);   // gate*2048 + w*8 + j
      int kb = (kt << 5) + ((lane >> 4) << 3);
      const float* src = (kb < 512) ? (W_ih + (size_t)row * 512 + kb)
                                    : (W_hh + (size_t)row * 2048 + (kb - 512));
      float4 u0 = *reinterpret_cast<const float4*>(src);
      float4 u1 = *reinterpret_cast<const float4*>(src + 4);
      bf16x8 v;
      v[0] = (short)f2bf(u0.x); v[1] = (short)f2bf(u0.y);
      v[2] = (short)f2bf(u0.z); v[3] = (short)f2bf(u0.w);
      v[4] = (short)f2bf(u1.x); v[5] = (short)f2bf(u1.y);
      v[6] = (short)f2bf(u1.z); v[7] = (short)f2bf(u1.w);
      *reinterpret_cast<bf16x8*>(Wbf + (size_t)slot * 8) = v;
    }
    const int NX = (Bb * Tt * Dd) / 8;
    for (int s = gtid; s < NX; s += NWG * NTHR) {
      const float* p = x + (size_t)s * 8;
      float4 u0 = *reinterpret_cast<const float4*>(p);
      float4 u1 = *reinterpret_cast<const float4*>(p + 4);
      bf16x8 v;
      v[0] = (short)f2bf(u0.x); v[1] = (short)f2bf(u0.y);
      v[2] = (short)f2bf(u0.z); v[3] = (short)f2bf(u0.w);
      v[4] = (short)f2bf(u1.x); v[5] = (short)f2bf(u1.y);
      v[6] = (short)f2bf(u1.z); v[7] = (short)f2bf(u1.w);
      *reinterpret_cast<bf16x8*>((short*)xbf + (size_t)s * 8) = v;
    }
    if (gtid < NWG)
      __hip_atomic_store(&flags[gtid], 0u, __ATOMIC_RELAXED, __HIP_MEMORY_SCOPE_AGENT);
    if (gtid < 8192) bsum[gtid] = b_ih[gtid] + b_hh[gtid];
  }
  grid.sync();

  // ---------- phase 0c: h0 / c0 ----------
  {
    for (int q = tid; q < 1024; q += NTHR) {
      int which = q >> 9;                 // 0 -> h0, 1 -> c0
      int b = (q >> 3) & 63;
      int j = q & 7;
      int n = (wg << 3) + j;
      const float* Wr = (which ? W_c0 : W_h0) + (size_t)n * 512;
      const float* mx = meanx + b * 512;
      float acc0 = which ? b_c0[n] : b_h0[n];
      for (int d = 0; d < 512; ++d) acc0 += mx[d] * Wr[d];
      if (which) cbuf[b * Hh + n] = acc0;
      else       Hbuf[(size_t)b * Hh + n] = f2bf(acc0);
    }
  }
  grid.sync();

  // ---------- pin w0 in registers (80 VGPR); q1 streamed from L2 (r6 structure) ----------
  const int wave = tid >> 6, lane = tid & 63;
  const int ml = lane & 15;
  const int kg = lane >> 4;
  const short* wb0 = Wbf + (size_t)(wg * 2) * NKT * 512;  // frag stride = 512 shorts
  const short* wb1 = wb0 + (size_t)NKT * 512;

  bf16x8 w0x[4], w0h[16];
#pragma unroll
  for (int i = 0; i < 4; ++i) {
    int kt = (wave << 2) + i;
    w0x[i] = *reinterpret_cast<const bf16x8*>(wb0 + ((size_t)kt << 9) + (lane << 3));
  }
#pragma unroll
  for (int i = 0; i < 16; ++i) {
    int kt = 16 + (wave << 4) + i;
    w0h[i] = *reinterpret_cast<const bf16x8*>(wb0 + ((size_t)kt << 9) + (lane << 3));
  }

  // ---------- hoist loop-invariant cell state into registers ----------
  const int cb = tid >> 2, cj0 = (tid & 3) << 1;
  const int cn0 = (wg << 3) + cj0;
  float cv0 = cbuf[cb * Hh + cn0], cv1 = cbuf[cb * Hh + cn0 + 1];
  const float bi0 = bsum[cn0],        bfs0 = bsum[2048 + cn0];
  const float bg0 = bsum[4096 + cn0], bo0 = bsum[6144 + cn0];
  const float bi1 = bsum[cn0 + 1],        bfs1 = bsum[2048 + cn0 + 1];
  const float bg1 = bsum[4096 + cn0 + 1], bo1 = bsum[6144 + cn0 + 1];

  f32x4 acc[4][2];
#pragma unroll
  for (int mt = 0; mt < 4; ++mt) {
    acc[mt][0] = (f32x4){0.f, 0.f, 0.f, 0.f};
    acc[mt][1] = (f32x4){0.f, 0.f, 0.f, 0.f};
  }

  // x-part of step tx+1's gates (recurrence-independent; runs under the barrier)
  auto xpart = [&](int tx) {
#pragma unroll
    for (int i = 0; i < 4; ++i) {
      int kt = (wave << 2) + i;
      int kk = (kt << 5) + (kg << 3);
      const unsigned short* xb = xbf + (size_t)tx * Dd + kk;
      bf16x8 afr[4];
#pragma unroll
      for (int mt = 0; mt < 4; ++mt) {
        int m = (mt << 4) + ml;
        afr[mt] = *reinterpret_cast<const bf16x8*>(xb + (size_t)m * (Tt * Dd));
      }
      bf16x8 q1 = *reinterpret_cast<const bf16x8*>(wb1 + ((size_t)kt << 9) + (lane << 3));
#pragma unroll
      for (int mt = 0; mt < 4; ++mt) {
        acc[mt][0] = __builtin_amdgcn_mfma_f32_16x16x32_bf16(afr[mt], w0x[i], acc[mt][0], 0, 0, 0);
        acc[mt][1] = __builtin_amdgcn_mfma_f32_16x16x32_bf16(afr[mt], q1, acc[mt][1], 0, 0, 0);
      }
    }
  };

  // contention-free barrier poll: wave 0 reads all 256 flags (atomic loads, no RMW)
  auto waitstep = [&](unsigned tw) {
    if (wave == 0) {
      const unsigned* fl = flags + (lane << 2);
      for (;;) {
        unsigned m0 = __hip_atomic_load(&fl[0], __ATOMIC_RELAXED, __HIP_MEMORY_SCOPE_AGENT);
        unsigned m1 = __hip_atomic_load(&fl[1], __ATOMIC_RELAXED, __HIP_MEMORY_SCOPE_AGENT);
        unsigned m2 = __hip_atomic_load(&fl[2], __ATOMIC_RELAXED, __HIP_MEMORY_SCOPE_AGENT);
        unsigned m3 = __hip_atomic_load(&fl[3], __ATOMIC_RELAXED, __HIP_MEMORY_SCOPE_AGENT);
        unsigned mn = min(min(m0, m1), min(m2, m3));
        if (__all(mn >= tw)) break;
        __builtin_amdgcn_s_sleep(2);
      }
    }
    asm volatile("" ::: "memory");
    __syncthreads();
  };

  // prologue: x-part for step 1 (x index 0)
  xpart(0);

  // ---------- main recurrence ----------
  for (int t = 1; t <= Tt; ++t) {
    if (t > 1) waitstep((unsigned)(t - 1));
    // h-part: 16 h k-tiles per wave; w0 regs, q1 streamed (L2-resident)
#pragma unroll
    for (int i = 0; i < 16; ++i) {
      int kt = 16 + (wave << 4) + i;
      int kk = (((wave << 4) + i) << 5) + (kg << 3);
      const unsigned short* hb = Hbuf + (size_t)(t - 1) * (Bb * Hh) + kk;
      bf16x8 afr[4];
#pragma unroll
      for (int mt = 0; mt < 4; ++mt) {
        int m = (mt << 4) + ml;
        afr[mt] = *reinterpret_cast<const bf16x8*>(hb + (size_t)m * Hh);
      }
      bf16x8 q1 = *reinterpret_cast<const bf16x8*>(wb1 + ((size_t)kt << 9) + (lane << 3));
#pragma unroll
      for (int mt = 0; mt < 4; ++mt) {
        acc[mt][0] = __builtin_amdgcn_mfma_f32_16x16x32_bf16(afr[mt], w0h[i], acc[mt][0], 0, 0, 0);
        acc[mt][1] = __builtin_amdgcn_mfma_f32_16x16x32_bf16(afr[mt], q1, acc[mt][1], 0, 0, 0);
      }
    }
    // partials -> LDS  (D layout: row=(lane>>4)*4+r, col=lane&15)
#pragma unroll
    for (int mt = 0; mt < 4; ++mt) {
      int r0 = (mt << 4) + (kg << 2);
#pragma unroll
      for (int r = 0; r < 4; ++r) {
        smem[((wave << 6) + r0 + r) * 33 + ml] = acc[mt][0][r];
        smem[((wave << 6) + r0 + r) * 33 + 16 + ml] = acc[mt][1][r];
      }
    }
    __syncthreads();
    // cell: reduce 4 wave-partials, LSTM nonlinearity (register cell state)
    unsigned* hout32 = (unsigned*)(Hbuf + (size_t)t * (Bb * Hh));
    {
      float gi0 = 0.f, gf_0 = 0.f, gg0 = 0.f, go0 = 0.f;
      float gi1 = 0.f, gf_1 = 0.f, gg1 = 0.f, go1 = 0.f;
#pragma unroll
      for (int w2 = 0; w2 < 4; ++w2) {
        const float* sp = &smem[((w2 << 6) + cb) * 33];
        gi0 += sp[cj0];          gf_0 += sp[8 + cj0];
        gg0 += sp[16 + cj0];     go0 += sp[24 + cj0];
        gi1 += sp[cj0 + 1];      gf_1 += sp[8 + cj0 + 1];
        gg1 += sp[16 + cj0 + 1]; go1 += sp[24 + cj0 + 1];
      }
      gi0 += bi0; gf_0 += bfs0; gg0 += bg0; go0 += bo0;
      gi1 += bi1; gf_1 += bfs1; gg1 += bg1; go1 += bo1;
      cv0 = sigm(gf_0) * cv0 + sigm(gi0) * tanh_(gg0);
      cv1 = sigm(gf_1) * cv1 + sigm(gi1) * tanh_(gg1);
      float hv0 = sigm(go0) * tanh_(cv0);
      float hv1 = sigm(go1) * tanh_(cv1);
      unsigned pk = ((unsigned)f2bf(hv1) << 16) | (unsigned)f2bf(hv0);
      __hip_atomic_store(&hout32[(cb * Hh + cn0) >> 1], pk,
                         __ATOMIC_RELAXED, __HIP_MEMORY_SCOPE_AGENT);
    }
    // drain h stores, arrive: one atomic STORE per WG (no RMW)
    asm volatile("s_waitcnt vmcnt(0)" ::: "memory");
    __syncthreads();
    if (tid == 0)
      __hip_atomic_store(&flags[wg], (unsigned)t,
                         __ATOMIC_RELAXED, __HIP_MEMORY_SCOPE_AGENT);
    // pipeline: x-part for step t+1 under the barrier wait
#pragma unroll
    for (int mt = 0; mt < 4; ++mt) {
      acc[mt][0] = (f32x4){0.f, 0.f, 0.f, 0.f};
      acc[mt][1] = (f32x4){0.f, 0.f, 0.f, 0.f};
    }
    if (t < Tt) xpart(t);
  }

  // ---------- wait for ALL WGs' step-512 h before reading it (race fix) ----------
  waitstep((unsigned)Tt);

  // ---------- fc epilogue ----------
  for (int i = tid; i < Oo * Hh; i += NTHR) smem[i] = W_fc[i];
  __syncthreads();
  if (gtid < Bb * Tt) {
    int b = gtid & 63, tq = gtid >> 6;
    const unsigned short* hrw = Hbuf + (size_t)(tq + 1) * (Bb * Hh) + (size_t)b * Hh;
    float acco[7];
#pragma unroll
    for (int o = 0; o < 7; ++o) acco[o] = b_fc[o];
    for (int k = 0; k < Hh; k += 8) {
      bf16x8 hv = *reinterpret_cast<const bf16x8*>(hrw + k);
      float hf[8];
#pragma unroll
      for (int e = 0; e < 8; ++e) hf[e] = bf2f((unsigned short)hv[e]);
#pragma unroll
      for (int o = 0; o < 7; ++o) {
        const float* wr = &smem[o * Hh + k];
        float s = 0.f;
#pragma unroll
        for (int e = 0; e < 8; ++e) s += hf[e] * wr[e];
        acco[o] += s;
      }
    }
    float* op = out + ((size_t)b * Tt + tq) * Oo;
#pragma unroll
    for (int o = 0; o < 7; ++o) op[o] = acco[o];
  }
}

extern "C" void kernel_launch(void* const* d_in, const int* in_sizes, int n_in,
                              void* d_out, int out_size, void* d_ws, size_t ws_size,
                              hipStream_t stream) {
  (void)in_sizes; (void)n_in;
  const float* x    = (const float*)d_in[0];
  const float* W_ih = (const float*)d_in[1];
  const float* b_ih = (const float*)d_in[2];
  const float* W_hh = (const float*)d_in[3];
  const float* b_hh = (const float*)d_in[4];
  const float* W_h0 = (const float*)d_in[5];
  const float* b_h0 = (const float*)d_in[6];
  const float* W_c0 = (const float*)d_in[7];
  const float* b_c0 = (const float*)d_in[8];
  const float* W_fc = (const float*)d_in[9];
  const float* b_fc = (const float*)d_in[10];
  float* out = (float*)d_out;

  char* ws = (char*)d_ws;
  size_t off = 0;
  short* Wbf = (short*)(ws + off);            off += (size_t)8192 * 2560 * 2;
  unsigned short* Hbuf = (unsigned short*)(ws + off); off += (size_t)513 * 64 * 2048 * 2;
  float* cbuf = (float*)(ws + off);           off += (size_t)64 * 2048 * 4;
  float* meanx = (float*)(ws + off);          off += (size_t)64 * 512 * 4;
  float* bsum = (float*)(ws + off);           off += (size_t)8192 * 4;
  unsigned short* xbf = (unsigned short*)(ws + off); off += (size_t)64 * 512 * 512 * 2;
  unsigned* flags = (unsigned*)(ws + off);    off += (size_t)NWG * 4;

  if (ws_size < off) {
    hipMemsetAsync(d_out, 0, (size_t)out_size * 4, stream);
    return;
  }

  void* args[] = {&x, &W_ih, &b_ih, &W_hh, &b_hh, &W_h0, &b_h0, &W_c0, &b_c0,
                  &W_fc, &b_fc, &out, &Wbf, &Hbuf, &cbuf, &meanx, &bsum, &xbf, &flags};
  hipLaunchCooperativeKernel((void*)lstm_fused, dim3(NWG), dim3(NTHR), args, 0, stream);
}

// Round 10
// 6526.701 us; speedup vs baseline: 1.4855x; 1.0288x over previous
//
#include <hip/hip_runtime.h>
#include <hip/hip_cooperative_groups.h>

namespace cg = cooperative_groups;

#define Bb 64
#define Tt 512
#define Dd 512
#define Hh 2048
#define Oo 7
#define NKT 80          // 2560 / 32
#define NWG 256
#define NTHR 512        // 8 waves -> 2 waves/SIMD

typedef short bf16x8 __attribute__((ext_vector_type(8)));
typedef float f32x4 __attribute__((ext_vector_type(4)));

__device__ __forceinline__ unsigned short f2bf(float f) {
  unsigned u = __float_as_uint(f);
  return (unsigned short)((u + 0x7FFFu + ((u >> 16) & 1u)) >> 16);
}
__device__ __forceinline__ float bf2f(unsigned short s) {
  return __uint_as_float(((unsigned)s) << 16);
}
__device__ __forceinline__ float sigm(float x) { return 1.0f / (1.0f + __expf(-x)); }
__device__ __forceinline__ float tanh_(float x) {
  x = fminf(15.0f, fmaxf(-15.0f, x));
  float e = __expf(2.0f * x);
  return (e - 1.0f) / (e + 1.0f);
}

__global__ void __launch_bounds__(NTHR, 2) lstm_fused(
    const float* __restrict__ x,
    const float* __restrict__ W_ih, const float* __restrict__ b_ih,
    const float* __restrict__ W_hh, const float* __restrict__ b_hh,
    const float* __restrict__ W_h0, const float* __restrict__ b_h0,
    const float* __restrict__ W_c0, const float* __restrict__ b_c0,
    const float* __restrict__ W_fc, const float* __restrict__ b_fc,
    float* __restrict__ out,
    short* __restrict__ Wbf,            // [8192*2560] bf16, fragment-linear
    unsigned short* __restrict__ Hbuf,  // [513][64][2048] bf16
    float* __restrict__ cbuf,           // [64][2048]
    float* __restrict__ meanx,          // [64][512]
    float* __restrict__ bsum,           // [8192]
    unsigned short* __restrict__ xbf,   // [64][512][512] bf16
    unsigned* __restrict__ flags)       // [256] per-WG step flag (monotonic)
{
  const int wg = blockIdx.x, tid = threadIdx.x;
  const int gtid = wg * NTHR + tid;
  cg::grid_group grid = cg::this_grid();
  __shared__ float smem[8 * 64 * 33];  // 67584 B: partials / phase0 / fc staging

  // ---------- phase 0a: mean_x over T ----------
  {
    int b = wg >> 2;
    int d = ((wg & 3) << 7) + (tid & 127);
    int th = tid >> 7;                   // 0..3, 128 timesteps each
    const float* xp = x + (size_t)b * Tt * Dd + d;
    float s = 0.f;
    for (int t = th * 128; t < th * 128 + 128; ++t) s += xp[(size_t)t * Dd];
    smem[tid] = s;
    __syncthreads();
    if (tid < 128) {
      float tot = smem[tid] + smem[tid + 128] + smem[tid + 256] + smem[tid + 384];
      meanx[b * Dd + ((wg & 3) << 7) + tid] = tot * (1.0f / Tt);
    }
    __syncthreads();
  }

  // ---------- phase 0b: weight swizzle + x->bf16 + bias sums + flag zero ----------
  {
    const int NSLOT = (8192 * 2560) / 8;
    for (int slot = gtid; slot < NSLOT; slot += NWG * NTHR) {
      int lane = slot & 63;
      int fr = slot >> 6;                 // ((wg*2+nt)*80 + kt)
      int kt = fr % 80;
      int ntw = fr / 80;                  // wg*2 + nt
      int nl = ((ntw & 1) << 4) + (lane & 15);
      int w = ntw >> 1;
      int row = ((nl >> 3) << 11) + (w << 3) + (nl & 7);   // gate*2048 + w*8 + j
      int kb = (kt << 5) + ((lane >> 4) << 3);
      const float* src = (kb < 512) ? (W_ih + (size_t)row * 512 + kb)
                                    : (W_hh + (size_t)row * 2048 + (kb - 512));
      float4 u0 = *reinterpret_cast<const float4*>(src);
      float4 u1 = *reinterpret_cast<const float4*>(src + 4);
      bf16x8 v;
      v[0] = (short)f2bf(u0.x); v[1] = (short)f2bf(u0.y);
      v[2] = (short)f2bf(u0.z); v[3] = (short)f2bf(u0.w);
      v[4] = (short)f2bf(u1.x); v[5] = (short)f2bf(u1.y);
      v[6] = (short)f2bf(u1.z); v[7] = (short)f2bf(u1.w);
      *reinterpret_cast<bf16x8*>(Wbf + (size_t)slot * 8) = v;
    }
    const int NX = (Bb * Tt * Dd) / 8;
    for (int s = gtid; s < NX; s += NWG * NTHR) {
      const float* p = x + (size_t)s * 8;
      float4 u0 = *reinterpret_cast<const float4*>(p);
      float4 u1 = *reinterpret_cast<const float4*>(p + 4);
      bf16x8 v;
      v[0] = (short)f2bf(u0.x); v[1] = (short)f2bf(u0.y);
      v[2] = (short)f2bf(u0.z); v[3] = (short)f2bf(u0.w);
      v[4] = (short)f2bf(u1.x); v[5] = (short)f2bf(u1.y);
      v[6] = (short)f2bf(u1.z); v[7] = (short)f2bf(u1.w);
      *reinterpret_cast<bf16x8*>((short*)xbf + (size_t)s * 8) = v;
    }
    if (gtid < NWG)
      __hip_atomic_store(&flags[gtid], 0u, __ATOMIC_RELAXED, __HIP_MEMORY_SCOPE_AGENT);
    if (gtid < 8192) bsum[gtid] = b_ih[gtid] + b_hh[gtid];
  }
  grid.sync();

  // ---------- phase 0c: h0 / c0 ----------
  {
    for (int q = tid; q < 1024; q += NTHR) {
      int which = q >> 9;                 // 0 -> h0, 1 -> c0
      int b = (q >> 3) & 63;
      int j = q & 7;
      int n = (wg << 3) + j;
      const float* Wr = (which ? W_c0 : W_h0) + (size_t)n * 512;
      const float* mx = meanx + b * 512;
      float acc0 = which ? b_c0[n] : b_h0[n];
      for (int d = 0; d < 512; ++d) acc0 += mx[d] * Wr[d];
      if (which) cbuf[b * Hh + n] = acc0;
      else       Hbuf[(size_t)b * Hh + n] = f2bf(acc0);
    }
  }
  grid.sync();

  // ---------- pin w0 in registers (40 VGPR/wave); q1 streamed from L2 ----------
  const int wave = tid >> 6, lane = tid & 63;   // wave 0..7
  const int ml = lane & 15;
  const int kg = lane >> 4;
  const short* wb0 = Wbf + (size_t)(wg * 2) * NKT * 512;  // frag stride = 512 shorts
  const short* wb1 = wb0 + (size_t)NKT * 512;

  bf16x8 w0x[2], w0h[8];
#pragma unroll
  for (int i = 0; i < 2; ++i) {
    int kt = (wave << 1) + i;            // 0..15
    w0x[i] = *reinterpret_cast<const bf16x8*>(wb0 + ((size_t)kt << 9) + (lane << 3));
  }
#pragma unroll
  for (int i = 0; i < 8; ++i) {
    int kt = 16 + (wave << 3) + i;       // 16..79
    w0h[i] = *reinterpret_cast<const bf16x8*>(wb0 + ((size_t)kt << 9) + (lane << 3));
  }

  // ---------- hoist loop-invariant cell state into registers (1 col/thread) ----------
  const int cb = tid >> 3, cj = tid & 7;
  const int cn = (wg << 3) + cj;
  float cv = cbuf[cb * Hh + cn];
  const float bi = bsum[cn],        bfs = bsum[2048 + cn];
  const float bg = bsum[4096 + cn], bo = bsum[6144 + cn];

  f32x4 acc[4][2];
#pragma unroll
  for (int mt = 0; mt < 4; ++mt) {
    acc[mt][0] = (f32x4){0.f, 0.f, 0.f, 0.f};
    acc[mt][1] = (f32x4){0.f, 0.f, 0.f, 0.f};
  }

  // x-part of step tx+1's gates (recurrence-independent; runs under the barrier)
  auto xpart = [&](int tx) {
#pragma unroll
    for (int i = 0; i < 2; ++i) {
      int kt = (wave << 1) + i;
      int kk = (kt << 5) + (kg << 3);
      const unsigned short* xb = xbf + (size_t)tx * Dd + kk;
      bf16x8 afr[4];
#pragma unroll
      for (int mt = 0; mt < 4; ++mt) {
        int m = (mt << 4) + ml;
        afr[mt] = *reinterpret_cast<const bf16x8*>(xb + (size_t)m * (Tt * Dd));
      }
      bf16x8 q1 = *reinterpret_cast<const bf16x8*>(wb1 + ((size_t)kt << 9) + (lane << 3));
#pragma unroll
      for (int mt = 0; mt < 4; ++mt) {
        acc[mt][0] = __builtin_amdgcn_mfma_f32_16x16x32_bf16(afr[mt], w0x[i], acc[mt][0], 0, 0, 0);
        acc[mt][1] = __builtin_amdgcn_mfma_f32_16x16x32_bf16(afr[mt], q1, acc[mt][1], 0, 0, 0);
      }
    }
  };

  // contention-free barrier poll: wave 0 reads all 256 flags (atomic loads, no RMW)
  auto waitstep = [&](unsigned tw) {
    if (wave == 0) {
      const unsigned* fl = flags + (lane << 2);
      for (;;) {
        unsigned m0 = __hip_atomic_load(&fl[0], __ATOMIC_RELAXED, __HIP_MEMORY_SCOPE_AGENT);
        unsigned m1 = __hip_atomic_load(&fl[1], __ATOMIC_RELAXED, __HIP_MEMORY_SCOPE_AGENT);
        unsigned m2 = __hip_atomic_load(&fl[2], __ATOMIC_RELAXED, __HIP_MEMORY_SCOPE_AGENT);
        unsigned m3 = __hip_atomic_load(&fl[3], __ATOMIC_RELAXED, __HIP_MEMORY_SCOPE_AGENT);
        unsigned mn = min(min(m0, m1), min(m2, m3));
        if (__all(mn >= tw)) break;
        __builtin_amdgcn_s_sleep(2);
      }
    }
    asm volatile("" ::: "memory");
    __syncthreads();
  };

  // prologue: x-part for step 1 (x index 0)
  xpart(0);

  // ---------- main recurrence ----------
  for (int t = 1; t <= Tt; ++t) {
    if (t > 1) waitstep((unsigned)(t - 1));
    // h-part: 8 h k-tiles per wave; w0 regs, q1 streamed (L2-resident)
#pragma unroll
    for (int i = 0; i < 8; ++i) {
      int kt = 16 + (wave << 3) + i;
      int kk = (((wave << 3) + i) << 5) + (kg << 3);
      const unsigned short* hb = Hbuf + (size_t)(t - 1) * (Bb * Hh) + kk;
      bf16x8 afr[4];
#pragma unroll
      for (int mt = 0; mt < 4; ++mt) {
        int m = (mt << 4) + ml;
        afr[mt] = *reinterpret_cast<const bf16x8*>(hb + (size_t)m * Hh);
      }
      bf16x8 q1 = *reinterpret_cast<const bf16x8*>(wb1 + ((size_t)kt << 9) + (lane << 3));
#pragma unroll
      for (int mt = 0; mt < 4; ++mt) {
        acc[mt][0] = __builtin_amdgcn_mfma_f32_16x16x32_bf16(afr[mt], w0h[i], acc[mt][0], 0, 0, 0);
        acc[mt][1] = __builtin_amdgcn_mfma_f32_16x16x32_bf16(afr[mt], q1, acc[mt][1], 0, 0, 0);
      }
    }
    // partials -> LDS  (D layout: row=(lane>>4)*4+r, col=lane&15)
#pragma unroll
    for (int mt = 0; mt < 4; ++mt) {
      int r0 = (mt << 4) + (kg << 2);
#pragma unroll
      for (int r = 0; r < 4; ++r) {
        smem[((wave << 6) + r0 + r) * 33 + ml] = acc[mt][0][r];
        smem[((wave << 6) + r0 + r) * 33 + 16 + ml] = acc[mt][1][r];
      }
    }
    __syncthreads();
    // cell: reduce 8 wave-partials, LSTM nonlinearity (register cell state)
    unsigned* hout32 = (unsigned*)(Hbuf + (size_t)t * (Bb * Hh));
    {
      float gi = 0.f, gf_ = 0.f, gg = 0.f, go = 0.f;
#pragma unroll
      for (int w2 = 0; w2 < 8; ++w2) {
        const float* sp = &smem[((w2 << 6) + cb) * 33];
        gi += sp[cj];       gf_ += sp[8 + cj];
        gg += sp[16 + cj];  go += sp[24 + cj];
      }
      gi += bi; gf_ += bfs; gg += bg; go += bo;
      cv = sigm(gf_) * cv + sigm(gi) * tanh_(gg);
      float hv = sigm(go) * tanh_(cv);
      float hv_hi = __shfl_down(hv, 1);
      if (!(tid & 1)) {
        unsigned pk = ((unsigned)f2bf(hv_hi) << 16) | (unsigned)f2bf(hv);
        __hip_atomic_store(&hout32[(cb * Hh + cn) >> 1], pk,
                           __ATOMIC_RELAXED, __HIP_MEMORY_SCOPE_AGENT);
      }
    }
    // drain h stores, arrive: one atomic STORE per WG (no RMW)
    asm volatile("s_waitcnt vmcnt(0)" ::: "memory");
    __syncthreads();
    if (tid == 0)
      __hip_atomic_store(&flags[wg], (unsigned)t,
                         __ATOMIC_RELAXED, __HIP_MEMORY_SCOPE_AGENT);
    // pipeline: x-part for step t+1 under the barrier wait
#pragma unroll
    for (int mt = 0; mt < 4; ++mt) {
      acc[mt][0] = (f32x4){0.f, 0.f, 0.f, 0.f};
      acc[mt][1] = (f32x4){0.f, 0.f, 0.f, 0.f};
    }
    if (t < Tt) xpart(t);
  }

  // ---------- wait for ALL WGs' step-512 h before reading it ----------
  waitstep((unsigned)Tt);

  // ---------- fc epilogue (stage W_fc f32 in smem, 57344B <= 67584B) ----------
  for (int i = tid; i < Oo * Hh; i += NTHR) smem[i] = W_fc[i];
  __syncthreads();
  if (gtid < Bb * Tt) {
    int b = gtid & 63, tq = gtid >> 6;
    const unsigned short* hrw = Hbuf + (size_t)(tq + 1) * (Bb * Hh) + (size_t)b * Hh;
    float acco[7];
#pragma unroll
    for (int o = 0; o < 7; ++o) acco[o] = b_fc[o];
    for (int k = 0; k < Hh; k += 8) {
      bf16x8 hv = *reinterpret_cast<const bf16x8*>(hrw + k);
      float hf[8];
#pragma unroll
      for (int e = 0; e < 8; ++e) hf[e] = bf2f((unsigned short)hv[e]);
#pragma unroll
      for (int o = 0; o < 7; ++o) {
        const float* wr = &smem[o * Hh + k];
        float s = 0.f;
#pragma unroll
        for (int e = 0; e < 8; ++e) s += hf[e] * wr[e];
        acco[o] += s;
      }
    }
    float* op = out + ((size_t)b * Tt + tq) * Oo;
#pragma unroll
    for (int o = 0; o < 7; ++o) op[o] = acco[o];
  }
}

extern "C" void kernel_launch(void* const* d_in, const int* in_sizes, int n_in,
                              void* d_out, int out_size, void* d_ws, size_t ws_size,
                              hipStream_t stream) {
  (void)in_sizes; (void)n_in;
  const float* x    = (const float*)d_in[0];
  const float* W_ih = (const float*)d_in[1];
  const float* b_ih = (const float*)d_in[2];
  const float* W_hh = (const float*)d_in[3];
  const float* b_hh = (const float*)d_in[4];
  const float* W_h0 = (const float*)d_in[5];
  const float* b_h0 = (const float*)d_in[6];
  const float* W_c0 = (const float*)d_in[7];
  const float* b_c0 = (const float*)d_in[8];
  const float* W_fc = (const float*)d_in[9];
  const float* b_fc = (const float*)d_in[10];
  float* out = (float*)d_out;

  char* ws = (char*)d_ws;
  size_t off = 0;
  short* Wbf = (short*)(ws + off);            off += (size_t)8192 * 2560 * 2;
  unsigned short* Hbuf = (unsigned short*)(ws + off); off += (size_t)513 * 64 * 2048 * 2;
  float* cbuf = (float*)(ws + off);           off += (size_t)64 * 2048 * 4;
  float* meanx = (float*)(ws + off);          off += (size_t)64 * 512 * 4;
  float* bsum = (float*)(ws + off);           off += (size_t)8192 * 4;
  unsigned short* xbf = (unsigned short*)(ws + off); off += (size_t)64 * 512 * 512 * 2;
  unsigned* flags = (unsigned*)(ws + off);    off += (size_t)NWG * 4;

  if (ws_size < off) {
    hipMemsetAsync(d_out, 0, (size_t)out_size * 4, stream);
    return;
  }

  void* args[] = {&x, &W_ih, &b_ih, &W_hh, &b_hh, &W_h0, &b_h0, &W_c0, &b_c0,
                  &W_fc, &b_fc, &out, &Wbf, &Hbuf, &cbuf, &meanx, &bsum, &xbf, &flags};
  hipLaunchCooperativeKernel((void*)lstm_fused, dim3(NWG), dim3(NTHR), args, 0, stream);
}